// Round 7
// baseline (4805.329 us; speedup 1.0000x reference)
//
#include <hip/hip_runtime.h>
#include <hip/hip_bf16.h>
#include <stdint.h>

typedef __hip_bfloat16 bf16;
typedef __attribute__((ext_vector_type(4))) float f32x4;
typedef __attribute__((ext_vector_type(8))) short bf16x8;

// Problem constants
#define BB   8
#define TT   2048
#define DD   1024
#define MM   (BB * TT)   // 16384 rows

enum { EPI_Q = 0, EPI_K, EPI_V, EPI_ND, EPI_MLP1, EPI_MLP2 };

static __device__ __forceinline__ void async_ld16(const bf16* g, bf16* l) {
  __builtin_amdgcn_global_load_lds(
      (const __attribute__((address_space(1))) void*)g,
      (__attribute__((address_space(3))) void*)l, 16, 0, 0);
}

// ---------------------------------------------------------------------------
// Universal GEMM: C[M,N] = A[M,K] @ B[N,K]^T, A/B bf16 row-major (K inner).
//
// 256x256 tile, BK=32, 512 threads (8 waves as 2Mx4N, each owning 128x64).
//
// ROUND-7 CHANGE (occupancy lever): rounds 3-6 tried three phase anatomies
// at 128 KiB LDS / 1 block/CU and all plateaued at 38-42% MfmaUtil --
// with one barrier-locked block per CU, read-bursts and MFMA-bursts
// alternate and nothing fills the gaps.  This round: 2-buffer ring =
// 64 KiB LDS -> 2 blocks/CU (launch_bounds(512,4)); the co-resident
// block's MFMA hides this block's stage/drain stalls (m97/m114: implicit
// inter-block overlap captures what source pipelining would add).
//
// Per K-tile: { stage(t+1) ; 12 ds_reads ; lgkm(4) ; 16 MFMA (A) ;
//               lgkm(0) ; 16 MFMA (B) ; vmcnt(0) ; barrier }
// ONE barrier per K-tile.  Safety: stage(t+1) writes buf[(t+1)&1], whose
// previous reads (tile t-1) drained before the end-of-(t-1) barrier
// (lgkm(0) precedes every MFMA-B which precedes the barrier); vmcnt(0)
// guarantees tile t+1 resident before its reads.  B-frag reads fly under
// MFMA-A (intra-wave overlap via counted lgkm).
//
// LDS bank swizzle (T2, verified 0 conflicts rounds 3/5/6): store global
// 16B chunk s ^ ((row>>1)&3) in LDS slot s by permuting the PER-LANE
// GLOBAL SOURCE column (LDS dest stays linear, as global_load_lds
// requires); read slot (lane>>4) ^ ((lane>>1)&3).
//
// Grid is 1-D with bijective XCD swizzle (all nwg % 8 == 0). EPI_ND decodes
// batch = XCD.  Requires: M,N % 256 == 0; K % 32 == 0; K/32 pow2 >= 2.
// ---------------------------------------------------------------------------
template<int EPI>
__global__ __launch_bounds__(512, 4)
void gemm_bt(const bf16* __restrict__ A, const bf16* __restrict__ B,
             int M, int N, int K,
             long long strideAz, long long strideBz,
             float* __restrict__ Cf,
             bf16* __restrict__ Cb, long long strideCz,
             const float* __restrict__ bias,
             const float* __restrict__ add,
             bf16* __restrict__ ekv)
{
  (void)M;
  // 2 buffers x (A 8192 + B 8192 elems) = 64 KiB
  __shared__ __align__(16) bf16 lds[32768];

  const int tid  = threadIdx.x;
  const int wave = tid >> 6;
  const int lane = tid & 63;

  // ---- XCD-aware swizzle on 1-D grid (nwg % 8 == 0 for every launch) ----
  const int nwg = (int)gridDim.x;
  const int bid = (int)blockIdx.x;
  const int swz = (bid & 7) * (nwg >> 3) + (bid >> 3);
  int bn, bm, bz;
  if constexpr (EPI == EPI_ND) {       // batch = XCD
    bn = swz & 7; bm = (swz >> 3) & 7; bz = swz >> 6;
  } else {
    const int nbn = N >> 8;            // power of two (4 / 16 / 64)
    const int lnb = 31 - __clz(nbn);
    bn = swz & (nbn - 1); bm = swz >> lnb; bz = 0;
  }
  A += (size_t)bz * strideAz;
  B += (size_t)bz * strideBz;

  const int wm = (wave >> 2) * 128;    // wave's M offset in tile
  const int wn = (wave & 3) * 64;      // wave's N offset in tile

  // ---- staging: per K-tile each thread issues 2 A + 2 B loads.
  // lane l -> row (wave*32 + (l>>2)); SOURCE chunk bank-swizzled:
  // (l&3) ^ ((l>>3)&3).  LDS dest = wave-uniform base + lane*16 (linear).
  const int lr = lane >> 2;            // 0..15
  const int lc = (((lane & 3) ^ ((lane >> 3) & 3))) * 8;  // swizzled src col
  const bf16* Ag0 = A + ((size_t)bm * 256 + wave * 32 + lr) * K + lc;
  const bf16* Bg0 = B + ((size_t)bn * 256 + wave * 32 + lr) * K + lc;
  const size_t K16 = (size_t)16 * K;   // 16 rows
  const int ldsAW = wave * 1024;       // wave's segment within A region
  const int NT = K >> 5;               // number of K-tiles (pow2 >= 2)

  auto stage = [&](int tt) {
    const int bo = (tt & 1) * 16384;
    const bf16* ga = Ag0 + (size_t)(tt & (NT - 1)) * 32;
    const bf16* gb = Bg0 + (size_t)(tt & (NT - 1)) * 32;
    async_ld16(ga,       &lds[bo + ldsAW]);
    async_ld16(ga + K16, &lds[bo + ldsAW + 512]);
    async_ld16(gb,       &lds[bo + 8192 + ldsAW]);
    async_ld16(gb + K16, &lds[bo + 8192 + ldsAW + 512]);
  };

  f32x4 acc[8][4];
#pragma unroll
  for (int i = 0; i < 8; ++i)
#pragma unroll
    for (int j = 0; j < 4; ++j) acc[i][j] = {0.f, 0.f, 0.f, 0.f};

  // ---- prologue: stage tile 0, drain, barrier ----
  stage(0);
  __builtin_amdgcn_sched_barrier(0);
  asm volatile("s_waitcnt vmcnt(0)" ::: "memory");
  __builtin_amdgcn_s_barrier();
  __builtin_amdgcn_sched_barrier(0);

  const int fm32 = (lane & 15) * 32;   // fragment row * row-stride
  // read slot = (lane>>4) ^ ((lane>>1)&3)   (bank swizzle, lane-constant)
  const int qs = (((lane >> 4) ^ ((lane >> 1) & 3))) * 8;

  for (int t = 0; t < NT; ++t) {
    const int bo = (t & 1) * 16384;
    const int ab = bo + wm * 32 + fm32 + qs;
    const int bb = bo + 8192 + wn * 32 + fm32 + qs;

    // stage next tile first: its HBM/L2 latency hides under this tile's
    // reads + MFMAs.  Target buffer's old reads drained before the
    // barrier that opened this tile.
    stage(t + 1);

    bf16x8 bfr[4], afA[4], afB[4];
#pragma unroll
    for (int j = 0; j < 4; ++j) bfr[j] = *(const bf16x8*)&lds[bb + j * 512];
#pragma unroll
    for (int i = 0; i < 4; ++i) afA[i] = *(const bf16x8*)&lds[ab + i * 512];
#pragma unroll
    for (int i = 0; i < 4; ++i)
      afB[i] = *(const bf16x8*)&lds[ab + 2048 + i * 512];
    __builtin_amdgcn_sched_barrier(0);
    asm volatile("s_waitcnt lgkmcnt(4)" ::: "memory");  // bfr+afA done
    __builtin_amdgcn_sched_barrier(0);
    __builtin_amdgcn_s_setprio(1);
#pragma unroll
    for (int i = 0; i < 4; ++i)
#pragma unroll
      for (int j = 0; j < 4; ++j)
        acc[i][j] = __builtin_amdgcn_mfma_f32_16x16x32_bf16(
            afA[i], bfr[j], acc[i][j], 0, 0, 0);
    __builtin_amdgcn_s_setprio(0);
    __builtin_amdgcn_sched_barrier(0);
    asm volatile("s_waitcnt lgkmcnt(0)" ::: "memory");  // afB done
    __builtin_amdgcn_sched_barrier(0);
    __builtin_amdgcn_s_setprio(1);
#pragma unroll
    for (int i = 0; i < 4; ++i)
#pragma unroll
      for (int j = 0; j < 4; ++j)
        acc[4 + i][j] = __builtin_amdgcn_mfma_f32_16x16x32_bf16(
            afB[i], bfr[j], acc[4 + i][j], 0, 0, 0);
    __builtin_amdgcn_s_setprio(0);
    __builtin_amdgcn_sched_barrier(0);
    asm volatile("s_waitcnt vmcnt(0)" ::: "memory");    // tile t+1 landed
    __builtin_amdgcn_s_barrier();
    __builtin_amdgcn_sched_barrier(0);
  }

  // ---- epilogue: C/D layout col=lane&15, row=(lane>>4)*4+reg ----
  const int cr = (lane >> 4) * 4;
  const int cc = lane & 15;
#pragma unroll
  for (int i = 0; i < 8; ++i) {
#pragma unroll
    for (int j = 0; j < 4; ++j) {
#pragma unroll
      for (int r = 0; r < 4; ++r) {
        const int gm = bm * 256 + wm + i * 16 + cr + r;
        const int gn = bn * 256 + wn + j * 16 + cc;
        float v = acc[i][j][r];
        if constexpr (EPI == EPI_Q) {
          v += bias[gn];
          Cb[(size_t)gm * N + gn] = __float2bfloat16(v);
        } else if constexpr (EPI == EPI_K) {
          // gm = d, gn = global s. ekvT[b][1024+d][t] = exp(k)
          v = __expf(v + bias[gm]);
          const int b = gn >> 11, t = gn & (TT - 1);
          ekv[((size_t)b << 22) + (size_t)(1024 + gm) * TT + t] =
              __float2bfloat16(v);
        } else if constexpr (EPI == EPI_V) {
          // ekvT[b][d][t] = ek * v
          v += bias[gm];
          const int b = gn >> 11, t = gn & (TT - 1);
          const size_t base = ((size_t)b << 22);
          const float ek =
              __bfloat162float(ekv[base + (size_t)(1024 + gm) * TT + t]);
          ekv[base + (size_t)gm * TT + t] = __float2bfloat16(v * ek);
        } else if constexpr (EPI == EPI_ND) {
          Cb[(size_t)bz * strideCz + (size_t)gm * N + gn] =
              __float2bfloat16(v);
        } else if constexpr (EPI == EPI_MLP1) {
          v = fmaxf(v + bias[gn], 0.0f);
          Cb[(size_t)gm * N + gn] = __float2bfloat16(v);
        } else {  // EPI_MLP2: add == Cf aliasing is safe (read-then-write
          // of the same element within the same thread)
          v += bias[gn] + add[(size_t)gm * N + gn];
          Cf[(size_t)gm * N + gn] = v;
        }
      }
    }
  }
}

// ---------------------------------------------------------------------------
// Transpose + cast fp32 [K,N] -> bf16 [N,K] (LDS tiled)
// ---------------------------------------------------------------------------
__global__ __launch_bounds__(256)
void transpose_cast(const float* __restrict__ W, bf16* __restrict__ Wt,
                    int K, int N)
{
  __shared__ float tile[32][33];
  const int n0 = blockIdx.x * 32, k0 = blockIdx.y * 32;
  const int tx = threadIdx.x, ty = threadIdx.y;  // 32 x 8
#pragma unroll
  for (int i = 0; i < 32; i += 8)
    tile[ty + i][tx] = W[(size_t)(k0 + ty + i) * N + n0 + tx];
  __syncthreads();
#pragma unroll
  for (int i = 0; i < 32; i += 8)
    Wt[(size_t)(n0 + ty + i) * K + k0 + tx] =
        __float2bfloat16(tile[tx][ty + i]);
}

// ---------------------------------------------------------------------------
// ew = exp(pos_bias) as bf16 (global max cancels in num/den ratio)
// ---------------------------------------------------------------------------
__global__ __launch_bounds__(256)
void ew_kernel(const float* __restrict__ pb, bf16* __restrict__ ew)
{
  const size_t gid = (size_t)blockIdx.x * 256 + threadIdx.x;
  const float4 v = *(const float4*)(pb + gid * 4);
  union { bf16 h[4]; unsigned long long u; } pk;
  pk.h[0] = __float2bfloat16(__expf(v.x));
  pk.h[1] = __float2bfloat16(__expf(v.y));
  pk.h[2] = __float2bfloat16(__expf(v.z));
  pk.h[3] = __float2bfloat16(__expf(v.w));
  *(unsigned long long*)(ew + gid * 4) = pk.u;
}

// ---------------------------------------------------------------------------
// LayerNorm over D=1024, one block per row, output bf16
// ---------------------------------------------------------------------------
__global__ __launch_bounds__(256)
void ln_kernel(const float* __restrict__ x, const float* __restrict__ g,
               const float* __restrict__ b, bf16* __restrict__ out)
{
  const int row = blockIdx.x;
  const int tid = threadIdx.x;
  const float4 v = ((const float4*)(x + (size_t)row * DD))[tid];
  float s  = v.x + v.y + v.z + v.w;
  float s2 = v.x * v.x + v.y * v.y + v.z * v.z + v.w * v.w;
#pragma unroll
  for (int o = 32; o; o >>= 1) {
    s  += __shfl_down(s, o);
    s2 += __shfl_down(s2, o);
  }
  __shared__ float red[8];
  if ((tid & 63) == 0) { red[tid >> 6] = s; red[4 + (tid >> 6)] = s2; }
  __syncthreads();
  const float ts  = red[0] + red[1] + red[2] + red[3];
  const float ts2 = red[4] + red[5] + red[6] + red[7];
  const float mu = ts * (1.0f / DD);
  const float rs = rsqrtf(ts2 * (1.0f / DD) - mu * mu + 1e-5f);
  const float4 gv = ((const float4*)g)[tid];
  const float4 bv = ((const float4*)b)[tid];
  union { bf16 h[4]; unsigned long long u; } pk;
  pk.h[0] = __float2bfloat16((v.x - mu) * rs * gv.x + bv.x);
  pk.h[1] = __float2bfloat16((v.y - mu) * rs * gv.y + bv.y);
  pk.h[2] = __float2bfloat16((v.z - mu) * rs * gv.z + bv.z);
  pk.h[3] = __float2bfloat16((v.w - mu) * rs * gv.w + bv.w);
  ((unsigned long long*)(out + (size_t)row * DD))[tid] = pk.u;
}

// ---------------------------------------------------------------------------
// Fused: x2 = sigmoid(q) * num/den + x  (x2 aliases d_out), then
// h2 = LN(x2, g2, b2) -> hout bf16.  One block per row.
// ---------------------------------------------------------------------------
__global__ __launch_bounds__(256)
void combine_ln_kernel(const bf16* __restrict__ q, const bf16* __restrict__ nd,
                       const float* __restrict__ x,
                       const float* __restrict__ g, const float* __restrict__ b,
                       float* __restrict__ x2, bf16* __restrict__ hout)
{
  const int row = blockIdx.x;
  const int tid = threadIdx.x;
  const int c = tid * 4;
  const bf16* ndr = nd + (size_t)row * 2048;
  union { unsigned long long u; bf16 h[4]; } un, ud, uq;
  un.u = *(const unsigned long long*)(ndr + c);
  ud.u = *(const unsigned long long*)(ndr + 1024 + c);
  uq.u = *(const unsigned long long*)(q + (size_t)row * DD + c);
  const float4 xv = *(const float4*)(x + (size_t)row * DD + c);
  float4 o;
  o.x = xv.x + (__bfloat162float(un.h[0]) / __bfloat162float(ud.h[0])) /
                   (1.0f + __expf(-__bfloat162float(uq.h[0])));
  o.y = xv.y + (__bfloat162float(un.h[1]) / __bfloat162float(ud.h[1])) /
                   (1.0f + __expf(-__bfloat162float(uq.h[1])));
  o.z = xv.z + (__bfloat162float(un.h[2]) / __bfloat162float(ud.h[2])) /
                   (1.0f + __expf(-__bfloat162float(uq.h[2])));
  o.w = xv.w + (__bfloat162float(un.h[3]) / __bfloat162float(ud.h[3])) /
                   (1.0f + __expf(-__bfloat162float(uq.h[3])));
  *(float4*)(x2 + (size_t)row * DD + c) = o;

  // ---- LayerNorm of o across the row ----
  float s  = o.x + o.y + o.z + o.w;
  float s2 = o.x * o.x + o.y * o.y + o.z * o.z + o.w * o.w;
#pragma unroll
  for (int off = 32; off; off >>= 1) {
    s  += __shfl_down(s, off);
    s2 += __shfl_down(s2, off);
  }
  __shared__ float red[8];
  if ((tid & 63) == 0) { red[tid >> 6] = s; red[4 + (tid >> 6)] = s2; }
  __syncthreads();
  const float ts  = red[0] + red[1] + red[2] + red[3];
  const float ts2 = red[4] + red[5] + red[6] + red[7];
  const float mu = ts * (1.0f / DD);
  const float rs = rsqrtf(ts2 * (1.0f / DD) - mu * mu + 1e-5f);
  const float4 gv = ((const float4*)g)[tid];
  const float4 bv = ((const float4*)b)[tid];
  union { bf16 h[4]; unsigned long long u; } pk;
  pk.h[0] = __float2bfloat16((o.x - mu) * rs * gv.x + bv.x);
  pk.h[1] = __float2bfloat16((o.y - mu) * rs * gv.y + bv.y);
  pk.h[2] = __float2bfloat16((o.z - mu) * rs * gv.z + bv.z);
  pk.h[3] = __float2bfloat16((o.w - mu) * rs * gv.w + bv.w);
  ((unsigned long long*)(hout + (size_t)row * DD))[tid] = pk.u;
}

// ---------------------------------------------------------------------------
extern "C" void kernel_launch(void* const* d_in, const int* in_sizes, int n_in,
                              void* d_out, int out_size, void* d_ws,
                              size_t ws_size, hipStream_t stream)
{
  (void)in_sizes; (void)n_in; (void)out_size; (void)ws_size;
  const float* x   = (const float*)d_in[0];
  const float* Wq  = (const float*)d_in[1];
  const float* bq  = (const float*)d_in[2];
  const float* Wk  = (const float*)d_in[3];
  const float* bk  = (const float*)d_in[4];
  const float* Wv  = (const float*)d_in[5];
  const float* bv  = (const float*)d_in[6];
  const float* pb  = (const float*)d_in[7];
  const float* g1  = (const float*)d_in[8];
  const float* be1 = (const float*)d_in[9];
  const float* W1  = (const float*)d_in[10];
  const float* bm1 = (const float*)d_in[11];
  const float* W2  = (const float*)d_in[12];
  const float* bm2 = (const float*)d_in[13];
  const float* g2  = (const float*)d_in[14];
  const float* be2 = (const float*)d_in[15];
  float* out = (float*)d_out;

  // ---- workspace layout: 222 MiB total ----
  const size_t MiB = 1024 * 1024;
  char* w = (char*)d_ws;
  bf16* hbf = (bf16*)w;  w += (size_t)MM * DD * 2;        // 32 MiB (h, then h2)
  bf16* wqt = (bf16*)w;  w += (size_t)DD * DD * 2;        // 2 MiB
  bf16* wkt = (bf16*)w;  w += (size_t)DD * DD * 2;
  bf16* wvt = (bf16*)w;  w += (size_t)DD * DD * 2;
  bf16* w1t = (bf16*)w;  w += (size_t)4096 * DD * 2;      // 8 MiB
  bf16* w2t = (bf16*)w;  w += (size_t)DD * 4096 * 2;      // 8 MiB
  // scratch region (168 MiB), fully dead after combine_ln_kernel:
  char* scr = w;
  bf16* qbf = (bf16*)scr;                                  // 32 MiB
  bf16* ewb = (bf16*)(scr + 32 * MiB);                     // 8 MiB
  bf16* ekv = (bf16*)(scr + 40 * MiB);   // 64 MiB [b][2048: 0..1023=ek*v, 1024..2047=ek][t]
  bf16* nd  = (bf16*)(scr + 104 * MiB);  // 64 MiB [b][t][2048: num|den]
  bf16* mid = (bf16*)scr;                // 128 MiB, overlays scratch after combine
  float* x2 = out;                       // alias: residual lives in d_out

  const dim3 tb(32, 8);
  transpose_cast<<<dim3(DD / 32, DD / 32), tb, 0, stream>>>(Wq, wqt, DD, DD);
  transpose_cast<<<dim3(DD / 32, DD / 32), tb, 0, stream>>>(Wk, wkt, DD, DD);
  transpose_cast<<<dim3(DD / 32, DD / 32), tb, 0, stream>>>(Wv, wvt, DD, DD);
  transpose_cast<<<dim3(4096 / 32, DD / 32), tb, 0, stream>>>(W1, w1t, DD, 4096);
  transpose_cast<<<dim3(DD / 32, 4096 / 32), tb, 0, stream>>>(W2, w2t, 4096, DD);

  ew_kernel<<<(TT * TT / 4) / 256, 256, 0, stream>>>(pb, ewb);
  ln_kernel<<<MM, 256, 0, stream>>>(x, g1, be1, hbf);

  // q = h @ Wq + bq  -> qbf [16384,1024] bf16
  gemm_bt<EPI_Q><<<(MM / 256) * (DD / 256), 512, 0, stream>>>(
      hbf, wqt, MM, DD, DD, 0, 0, nullptr, qbf, 0, bq, nullptr, nullptr);
  // ek^T: C[d, s] = Wkt @ h^T, epilogue exp -> ekv rows 1024..2047
  gemm_bt<EPI_K><<<(DD / 256) * (MM / 256), 512, 0, stream>>>(
      wkt, hbf, DD, MM, DD, 0, 0, nullptr, nullptr, 0, bk, nullptr, ekv);
  // v^T: epilogue *ek -> ekv rows 0..1023
  gemm_bt<EPI_V><<<(DD / 256) * (MM / 256), 512, 0, stream>>>(
      wvt, hbf, DD, MM, DD, 0, 0, nullptr, nullptr, 0, bv, nullptr, ekv);
  // nd[b] = ew @ ekv[b]^T : [2048,2048] bf16 per batch (XCD = batch)
  gemm_bt<EPI_ND><<<BB * (TT / 256) * (TT / 256), 512, 0, stream>>>(
      ewb, ekv, TT, TT, TT, 0, (long long)TT * TT, nullptr, nd,
      (long long)TT * TT, nullptr, nullptr, nullptr);

  // fused: x2 = sigmoid(q)*num/den + x ; hbf = LN(x2)
  combine_ln_kernel<<<MM, 256, 0, stream>>>(qbf, nd, x, g2, be2, x2, hbf);

  // mid = relu(h2 @ W1 + b1) bf16 [16384,4096]
  gemm_bt<EPI_MLP1><<<(MM / 256) * (4096 / 256), 512, 0, stream>>>(
      hbf, w1t, MM, 4096, DD, 0, 0, nullptr, mid, 0, bm1, nullptr, nullptr);
  // out = mid @ W2 + b2 + x2 fp32 [16384,1024]  (add == Cf, safe)
  gemm_bt<EPI_MLP2><<<(MM / 256) * (DD / 256), 512, 0, stream>>>(
      mid, w2t, MM, DD, 4096, 0, 0, out, nullptr, 0, bm2, x2, nullptr);
}

// Round 8
// 705.633 us; speedup vs baseline: 6.8100x; 6.8100x over previous
//
#include <hip/hip_runtime.h>
#include <hip/hip_bf16.h>
#include <stdint.h>

typedef __hip_bfloat16 bf16;
typedef __attribute__((ext_vector_type(4))) float f32x4;
typedef __attribute__((ext_vector_type(8))) short bf16x8;

// Problem constants
#define BB   8
#define TT   2048
#define DD   1024
#define MM   (BB * TT)   // 16384 rows

enum { EPI_Q = 0, EPI_KV, EPI_ND, EPI_MLP1, EPI_MLP2 };

static __device__ __forceinline__ void async_ld16(const bf16* g, bf16* l) {
  __builtin_amdgcn_global_load_lds(
      (const __attribute__((address_space(1))) void*)g,
      (__attribute__((address_space(3))) void*)l, 16, 0, 0);
}

// ---------------------------------------------------------------------------
// Universal GEMM: C[M,N] = A[M,K] @ B[N,K]^T, A/B bf16 row-major (K inner).
//
// ROUND-8: GEMM engine reverted to the round-5 optimum (940 TF, 42%
// MfmaUtil, 0 bank conflicts).  Round-7's launch_bounds(512,4) forced a
// 128-VGPR cap -> acc spilled to scratch (WRITE_SIZE 4 GB, 4.5% MfmaUtil).
// A 256^2 tile NEEDS ~200 VGPR; 1 block/CU is structural.
//
// 256x256 tile, BK=32, 512 threads (8 waves as 2Mx4N, each owning 128x64).
// 4 LDS buffers (128 KiB); during K-tile t we stage K-tile t+3 into
// buf[(t+3)&3] == buf[(t-1)&3], whose reads all retired before the
// preceding barrier (counted lgkm waits).  vmcnt(6) once per K-tile keeps
// 3 stage-calls in flight ACROSS barriers and guarantees tile t+1 fully
// landed before its reads are issued.  Fragment ds_reads issued ONE PHASE
// AHEAD with ping-pong bfr sets (afA/afB rotate in place):
//   phase A: issue afB_t(4) reads; vmcnt(6) lgkm(4) retires bfr_t/afA_t;
//            MFMA A overlaps afB_t reads; barrier.
//   phase B: issue bfrX/afA_{t+1}(8) reads; lgkm(8) retires afB_t;
//            MFMA B overlaps next-tile reads; barrier.
//
// LDS bank swizzle (T2, verified 0 conflicts rounds 3/5/6): store global
// 16B chunk s ^ ((row>>1)&3) in LDS slot s by permuting the PER-LANE
// GLOBAL SOURCE column (LDS dest stays linear); read slot
// (lane>>4) ^ ((lane>>1)&3).
//
// EPI_KV (new): A is the row-interleaved [wk;wv] matrix (row 2d = wk[d],
// row 2d+1 = wv[d], M=2048).  Epilogue r-pairs (r,r+1), base row even,
// hold (k[d],v[d]) for the SAME (d,t) in the same thread -> compute
// ek=exp(k+bk) and ek*(v+bv) locally; no ekv read-back, one launch for
// K and V.  bias=bk, add=bv (as float*).
//
// Grid is 1-D with bijective XCD swizzle (all nwg % 8 == 0). EPI_ND decodes
// batch = XCD.  Requires: M,N % 256 == 0; K % 32 == 0; K/32 even pow2 >= 4.
// ---------------------------------------------------------------------------
template<int EPI>
__global__ __launch_bounds__(512, 2)
void gemm_bt(const bf16* __restrict__ A, const bf16* __restrict__ B,
             int M, int N, int K,
             long long strideAz, long long strideBz,
             float* __restrict__ Cf,
             bf16* __restrict__ Cb, long long strideCz,
             const float* __restrict__ bias,
             const float* __restrict__ add,
             bf16* __restrict__ ekv)
{
  (void)M;
  // A region: [0, 32768) elements (4 buffers x 8192), B: [32768, 65536)
  __shared__ __align__(16) bf16 lds[65536];

  const int tid  = threadIdx.x;
  const int wave = tid >> 6;
  const int lane = tid & 63;

  // ---- XCD-aware swizzle on 1-D grid (nwg % 8 == 0 for every launch) ----
  const int nwg = (int)gridDim.x;
  const int bid = (int)blockIdx.x;
  const int swz = (bid & 7) * (nwg >> 3) + (bid >> 3);
  int bn, bm, bz;
  if constexpr (EPI == EPI_ND) {       // batch = XCD
    bn = swz & 7; bm = (swz >> 3) & 7; bz = swz >> 6;
  } else {
    const int nbn = N >> 8;            // power of two (4 / 16 / 64)
    const int lnb = 31 - __clz(nbn);
    bn = swz & (nbn - 1); bm = swz >> lnb; bz = 0;
  }
  A += (size_t)bz * strideAz;
  B += (size_t)bz * strideBz;

  const int wm = (wave >> 2) * 128;    // wave's M offset in tile
  const int wn = (wave & 3) * 64;      // wave's N offset in tile

  // ---- staging: per K-tile each thread issues 2 A + 2 B loads.
  // lane l -> row (wave*32 + (l>>2)); SOURCE chunk bank-swizzled:
  // (l&3) ^ ((l>>3)&3).  LDS dest = wave-uniform base + lane*16 (linear).
  const int lr = lane >> 2;            // 0..15
  const int lc = (((lane & 3) ^ ((lane >> 3) & 3))) * 8;  // swizzled src col
  const bf16* Ag0 = A + ((size_t)bm * 256 + wave * 32 + lr) * K + lc;
  const bf16* Bg0 = B + ((size_t)bn * 256 + wave * 32 + lr) * K + lc;
  const size_t K16 = (size_t)16 * K;   // 16 rows
  const int ldsAW = wave * 1024;       // wave's segment (elements)
  const int ldsBW = 32768 + wave * 1024;
  const int NT = K >> 5;               // number of K-tiles (even pow2 >= 4)

  auto stageA = [&](int tt) {
    const int bo = (tt & 3) * 8192;
    const bf16* g = Ag0 + (size_t)(tt & (NT - 1)) * 32;
    async_ld16(g,       &lds[bo + ldsAW]);
    async_ld16(g + K16, &lds[bo + ldsAW + 512]);
  };
  auto stageB = [&](int tt) {
    const int bo = (tt & 3) * 8192;
    const bf16* g = Bg0 + (size_t)(tt & (NT - 1)) * 32;
    async_ld16(g,       &lds[bo + ldsBW]);
    async_ld16(g + K16, &lds[bo + ldsBW + 512]);
  };

  f32x4 acc[8][4];
#pragma unroll
  for (int i = 0; i < 8; ++i)
#pragma unroll
    for (int j = 0; j < 4; ++j) acc[i][j] = {0.f, 0.f, 0.f, 0.f};

  // ---- prologue: stage K-tiles 0,1,2; vmcnt(8) retires tile 0 ----
  stageA(0); stageB(0);
  stageA(1); stageB(1);
  stageA(2); stageB(2);
  __builtin_amdgcn_sched_barrier(0);
  asm volatile("s_waitcnt vmcnt(8)" ::: "memory");
  __builtin_amdgcn_s_barrier();
  __builtin_amdgcn_sched_barrier(0);

  const int fm32 = (lane & 15) * 32;   // fragment row * row-stride
  // read slot = (lane>>4) ^ ((lane>>1)&3)   (bank swizzle, lane-constant)
  const int qs = (((lane >> 4) ^ ((lane >> 1) & 3))) * 8;

  bf16x8 bfrP[4], bfrN[4], afA[4], afB[4];

  // initial reads for tile 0 (post-barrier: tile-0 buffer safe)
  {
    const int ab0 = wm * 32 + fm32 + qs;
    const int bb0 = 32768 + wn * 32 + fm32 + qs;
#pragma unroll
    for (int j = 0; j < 4; ++j) bfrP[j] = *(const bf16x8*)&lds[bb0 + j * 512];
#pragma unroll
    for (int i = 0; i < 4; ++i) afA[i] = *(const bf16x8*)&lds[ab0 + i * 512];
  }
  __builtin_amdgcn_sched_barrier(0);

#define TILE_BODY(t, bfrC, bfrX)                                               \
  {                                                                            \
    const int ab  = ((t) & 3) * 8192 + wm * 32 + fm32 + qs;                    \
    const int abn = (((t) + 1) & 3) * 8192 + wm * 32 + fm32 + qs;              \
    const int bbn = 32768 + (((t) + 1) & 3) * 8192 + wn * 32 + fm32 + qs;      \
    /* ---- phase A ---- */                                                    \
    _Pragma("unroll")                                                          \
    for (int i = 0; i < 4; ++i)                                                \
      afB[i] = *(const bf16x8*)&lds[ab + 2048 + i * 512];                      \
    stageA((t) + 3);                                                           \
    __builtin_amdgcn_sched_barrier(0);                                         \
    asm volatile("s_waitcnt vmcnt(6) lgkmcnt(4)" ::: "memory");                \
    __builtin_amdgcn_sched_barrier(0);                                         \
    __builtin_amdgcn_s_setprio(1);                                             \
    _Pragma("unroll")                                                          \
    for (int i = 0; i < 4; ++i)                                                \
      _Pragma("unroll")                                                        \
      for (int j = 0; j < 4; ++j)                                              \
        acc[i][j] = __builtin_amdgcn_mfma_f32_16x16x32_bf16(                   \
            afA[i], bfrC[j], acc[i][j], 0, 0, 0);                              \
    __builtin_amdgcn_s_setprio(0);                                             \
    __builtin_amdgcn_s_barrier();                                              \
    __builtin_amdgcn_sched_barrier(0);                                         \
    /* ---- phase B ---- */                                                    \
    _Pragma("unroll")                                                          \
    for (int j = 0; j < 4; ++j)                                                \
      bfrX[j] = *(const bf16x8*)&lds[bbn + j * 512];                           \
    _Pragma("unroll")                                                          \
    for (int i = 0; i < 4; ++i)                                                \
      afA[i] = *(const bf16x8*)&lds[abn + i * 512];                            \
    stageB((t) + 3);                                                           \
    __builtin_amdgcn_sched_barrier(0);                                         \
    asm volatile("s_waitcnt lgkmcnt(8)" ::: "memory");                         \
    __builtin_amdgcn_sched_barrier(0);                                         \
    __builtin_amdgcn_s_setprio(1);                                             \
    _Pragma("unroll")                                                          \
    for (int i = 0; i < 4; ++i)                                                \
      _Pragma("unroll")                                                        \
      for (int j = 0; j < 4; ++j)                                              \
        acc[4 + i][j] = __builtin_amdgcn_mfma_f32_16x16x32_bf16(               \
            afB[i], bfrC[j], acc[4 + i][j], 0, 0, 0);                          \
    __builtin_amdgcn_s_setprio(0);                                             \
    __builtin_amdgcn_s_barrier();                                              \
    __builtin_amdgcn_sched_barrier(0);                                         \
  }

  for (int tp = 0; tp < NT; tp += 2) {
    TILE_BODY(tp,     bfrP, bfrN);
    TILE_BODY(tp + 1, bfrN, bfrP);
  }
#undef TILE_BODY

  // ---- epilogue: C/D layout col=lane&15, row=(lane>>4)*4+reg ----
  const int cr = (lane >> 4) * 4;
  const int cc = lane & 15;
#pragma unroll
  for (int i = 0; i < 8; ++i) {
#pragma unroll
    for (int j = 0; j < 4; ++j) {
#pragma unroll
      for (int r = 0; r < 4; ++r) {
        const int gm = bm * 256 + wm + i * 16 + cr + r;
        const int gn = bn * 256 + wn + j * 16 + cc;
        float v = acc[i][j][r];
        if constexpr (EPI == EPI_Q) {
          v += bias[gn];
          Cb[(size_t)gm * N + gn] = __float2bfloat16(v);
        } else if constexpr (EPI == EPI_KV) {
          // interleaved rows: even gm = k[d], odd gm = v[d], d = gm>>1.
          // Base row (r=0) is provably even, so (r, r+1) pair shares d.
          if ((r & 1) == 0) {
            const int d = gm >> 1;
            const float ek = __expf(acc[i][j][r] + bias[d]);       // bk
            const float vv = acc[i][j][r + 1] + add[d];            // bv
            const int b = gn >> 11, t = gn & (TT - 1);
            const size_t base = ((size_t)b << 22);
            ekv[base + (size_t)(1024 + d) * TT + t] = __float2bfloat16(ek);
            ekv[base + (size_t)d * TT + t] = __float2bfloat16(ek * vv);
          }
        } else if constexpr (EPI == EPI_ND) {
          Cb[(size_t)bz * strideCz + (size_t)gm * N + gn] =
              __float2bfloat16(v);
        } else if constexpr (EPI == EPI_MLP1) {
          v = fmaxf(v + bias[gn], 0.0f);
          Cb[(size_t)gm * N + gn] = __float2bfloat16(v);
        } else {  // EPI_MLP2: add == Cf aliasing is safe (read-then-write
          // of the same element within the same thread)
          v += bias[gn] + add[(size_t)gm * N + gn];
          Cf[(size_t)gm * N + gn] = v;
        }
      }
    }
  }
}

// ---------------------------------------------------------------------------
// Transpose + cast fp32 [K,N] -> bf16 [N,K]; output row index = n*rs + ro
// (rs=2 interleaves two matrices row-wise into one destination).
// ---------------------------------------------------------------------------
__global__ __launch_bounds__(256)
void transpose_cast(const float* __restrict__ W, bf16* __restrict__ Wt,
                    int K, int N, int rs, int ro)
{
  __shared__ float tile[32][33];
  const int n0 = blockIdx.x * 32, k0 = blockIdx.y * 32;
  const int tx = threadIdx.x, ty = threadIdx.y;  // 32 x 8
#pragma unroll
  for (int i = 0; i < 32; i += 8)
    tile[ty + i][tx] = W[(size_t)(k0 + ty + i) * N + n0 + tx];
  __syncthreads();
#pragma unroll
  for (int i = 0; i < 32; i += 8)
    Wt[((size_t)(n0 + ty + i) * rs + ro) * K + k0 + tx] =
        __float2bfloat16(tile[tx][ty + i]);
}

// 3 square DDxDD transposes in one launch: z=0 Wq->wqt (linear),
// z=1 Wk->wkv rows 2d, z=2 Wv->wkv rows 2d+1.
__global__ __launch_bounds__(256)
void transpose3(const float* __restrict__ Wq, const float* __restrict__ Wk,
                const float* __restrict__ Wv, bf16* __restrict__ wqt,
                bf16* __restrict__ wkv)
{
  __shared__ float tile[32][33];
  const int z = blockIdx.z;
  const float* W = (z == 0) ? Wq : (z == 1) ? Wk : Wv;
  bf16* Wt = (z == 0) ? wqt : wkv;
  const int rs = (z == 0) ? 1 : 2;
  const int ro = (z == 2) ? 1 : 0;
  const int n0 = blockIdx.x * 32, k0 = blockIdx.y * 32;
  const int tx = threadIdx.x, ty = threadIdx.y;  // 32 x 8
#pragma unroll
  for (int i = 0; i < 32; i += 8)
    tile[ty + i][tx] = W[(size_t)(k0 + ty + i) * DD + n0 + tx];
  __syncthreads();
#pragma unroll
  for (int i = 0; i < 32; i += 8)
    Wt[((size_t)(n0 + ty + i) * rs + ro) * DD + k0 + tx] =
        __float2bfloat16(tile[tx][ty + i]);
}

// ---------------------------------------------------------------------------
// Fused: blocks [0,MM) do LayerNorm rows; blocks [MM, MM+4096) do
// ew = exp(pos_bias) (global max cancels in num/den ratio).
// ---------------------------------------------------------------------------
__global__ __launch_bounds__(256)
void ln_ew_kernel(const float* __restrict__ x, const float* __restrict__ g,
                  const float* __restrict__ b, bf16* __restrict__ out,
                  const float* __restrict__ pb, bf16* __restrict__ ew)
{
  const int blk = blockIdx.x;
  const int tid = threadIdx.x;
  if (blk >= MM) {  // ---- ew part ----
    const size_t gid = (size_t)(blk - MM) * 256 + tid;
    const float4 v = *(const float4*)(pb + gid * 4);
    union { bf16 h[4]; unsigned long long u; } pk;
    pk.h[0] = __float2bfloat16(__expf(v.x));
    pk.h[1] = __float2bfloat16(__expf(v.y));
    pk.h[2] = __float2bfloat16(__expf(v.z));
    pk.h[3] = __float2bfloat16(__expf(v.w));
    *(unsigned long long*)(ew + gid * 4) = pk.u;
    return;
  }
  // ---- LayerNorm row ----
  const int row = blk;
  const float4 v = ((const float4*)(x + (size_t)row * DD))[tid];
  float s  = v.x + v.y + v.z + v.w;
  float s2 = v.x * v.x + v.y * v.y + v.z * v.z + v.w * v.w;
#pragma unroll
  for (int o = 32; o; o >>= 1) {
    s  += __shfl_down(s, o);
    s2 += __shfl_down(s2, o);
  }
  __shared__ float red[8];
  if ((tid & 63) == 0) { red[tid >> 6] = s; red[4 + (tid >> 6)] = s2; }
  __syncthreads();
  const float ts  = red[0] + red[1] + red[2] + red[3];
  const float ts2 = red[4] + red[5] + red[6] + red[7];
  const float mu = ts * (1.0f / DD);
  const float rs = rsqrtf(ts2 * (1.0f / DD) - mu * mu + 1e-5f);
  const float4 gv = ((const float4*)g)[tid];
  const float4 bv = ((const float4*)b)[tid];
  union { bf16 h[4]; unsigned long long u; } pk;
  pk.h[0] = __float2bfloat16((v.x - mu) * rs * gv.x + bv.x);
  pk.h[1] = __float2bfloat16((v.y - mu) * rs * gv.y + bv.y);
  pk.h[2] = __float2bfloat16((v.z - mu) * rs * gv.z + bv.z);
  pk.h[3] = __float2bfloat16((v.w - mu) * rs * gv.w + bv.w);
  ((unsigned long long*)(out + (size_t)row * DD))[tid] = pk.u;
}

// ---------------------------------------------------------------------------
// Fused: x2 = sigmoid(q) * num/den + x  (x2 aliases d_out), then
// h2 = LN(x2, g2, b2) -> hout bf16.  One block per row.
// ---------------------------------------------------------------------------
__global__ __launch_bounds__(256)
void combine_ln_kernel(const bf16* __restrict__ q, const bf16* __restrict__ nd,
                       const float* __restrict__ x,
                       const float* __restrict__ g, const float* __restrict__ b,
                       float* __restrict__ x2, bf16* __restrict__ hout)
{
  const int row = blockIdx.x;
  const int tid = threadIdx.x;
  const int c = tid * 4;
  const bf16* ndr = nd + (size_t)row * 2048;
  union { unsigned long long u; bf16 h[4]; } un, ud, uq;
  un.u = *(const unsigned long long*)(ndr + c);
  ud.u = *(const unsigned long long*)(ndr + 1024 + c);
  uq.u = *(const unsigned long long*)(q + (size_t)row * DD + c);
  const float4 xv = *(const float4*)(x + (size_t)row * DD + c);
  float4 o;
  o.x = xv.x + (__bfloat162float(un.h[0]) / __bfloat162float(ud.h[0])) /
                   (1.0f + __expf(-__bfloat162float(uq.h[0])));
  o.y = xv.y + (__bfloat162float(un.h[1]) / __bfloat162float(ud.h[1])) /
                   (1.0f + __expf(-__bfloat162float(uq.h[1])));
  o.z = xv.z + (__bfloat162float(un.h[2]) / __bfloat162float(ud.h[2])) /
                   (1.0f + __expf(-__bfloat162float(uq.h[2])));
  o.w = xv.w + (__bfloat162float(un.h[3]) / __bfloat162float(ud.h[3])) /
                   (1.0f + __expf(-__bfloat162float(uq.h[3])));
  *(float4*)(x2 + (size_t)row * DD + c) = o;

  // ---- LayerNorm of o across the row ----
  float s  = o.x + o.y + o.z + o.w;
  float s2 = o.x * o.x + o.y * o.y + o.z * o.z + o.w * o.w;
#pragma unroll
  for (int off = 32; off; off >>= 1) {
    s  += __shfl_down(s, off);
    s2 += __shfl_down(s2, off);
  }
  __shared__ float red[8];
  if ((tid & 63) == 0) { red[tid >> 6] = s; red[4 + (tid >> 6)] = s2; }
  __syncthreads();
  const float ts  = red[0] + red[1] + red[2] + red[3];
  const float ts2 = red[4] + red[5] + red[6] + red[7];
  const float mu = ts * (1.0f / DD);
  const float rs = rsqrtf(ts2 * (1.0f / DD) - mu * mu + 1e-5f);
  const float4 gv = ((const float4*)g)[tid];
  const float4 bv = ((const float4*)b)[tid];
  union { bf16 h[4]; unsigned long long u; } pk;
  pk.h[0] = __float2bfloat16((o.x - mu) * rs * gv.x + bv.x);
  pk.h[1] = __float2bfloat16((o.y - mu) * rs * gv.y + bv.y);
  pk.h[2] = __float2bfloat16((o.z - mu) * rs * gv.z + bv.z);
  pk.h[3] = __float2bfloat16((o.w - mu) * rs * gv.w + bv.w);
  ((unsigned long long*)(hout + (size_t)row * DD))[tid] = pk.u;
}

// ---------------------------------------------------------------------------
extern "C" void kernel_launch(void* const* d_in, const int* in_sizes, int n_in,
                              void* d_out, int out_size, void* d_ws,
                              size_t ws_size, hipStream_t stream)
{
  (void)in_sizes; (void)n_in; (void)out_size; (void)ws_size;
  const float* x   = (const float*)d_in[0];
  const float* Wq  = (const float*)d_in[1];
  const float* bq  = (const float*)d_in[2];
  const float* Wk  = (const float*)d_in[3];
  const float* bk  = (const float*)d_in[4];
  const float* Wv  = (const float*)d_in[5];
  const float* bv  = (const float*)d_in[6];
  const float* pb  = (const float*)d_in[7];
  const float* g1  = (const float*)d_in[8];
  const float* be1 = (const float*)d_in[9];
  const float* W1  = (const float*)d_in[10];
  const float* bm1 = (const float*)d_in[11];
  const float* W2  = (const float*)d_in[12];
  const float* bm2 = (const float*)d_in[13];
  const float* g2  = (const float*)d_in[14];
  const float* be2 = (const float*)d_in[15];
  float* out = (float*)d_out;

  // ---- workspace layout: 222 MiB total ----
  const size_t MiB = 1024 * 1024;
  char* w = (char*)d_ws;
  bf16* hbf = (bf16*)w;  w += (size_t)MM * DD * 2;        // 32 MiB (h, then h2)
  bf16* wqt = (bf16*)w;  w += (size_t)DD * DD * 2;        // 2 MiB
  bf16* wkv = (bf16*)w;  w += (size_t)2 * DD * DD * 2;    // 4 MiB (interleaved)
  bf16* w1t = (bf16*)w;  w += (size_t)4096 * DD * 2;      // 8 MiB
  bf16* w2t = (bf16*)w;  w += (size_t)DD * 4096 * 2;      // 8 MiB
  // scratch region (168 MiB), fully dead after combine_ln_kernel:
  char* scr = w;
  bf16* qbf = (bf16*)scr;                                  // 32 MiB
  bf16* ewb = (bf16*)(scr + 32 * MiB);                     // 8 MiB
  bf16* ekv = (bf16*)(scr + 40 * MiB);   // 64 MiB [b][2048: 0..1023=ek*v, 1024..2047=ek][t]
  bf16* nd  = (bf16*)(scr + 104 * MiB);  // 64 MiB [b][t][2048: num|den]
  bf16* mid = (bf16*)scr;                // 128 MiB, overlays scratch after combine
  float* x2 = out;                       // alias: residual lives in d_out

  const dim3 tb(32, 8);
  transpose3<<<dim3(DD / 32, DD / 32, 3), tb, 0, stream>>>(Wq, Wk, Wv,
                                                           wqt, wkv);
  transpose_cast<<<dim3(4096 / 32, DD / 32), tb, 0, stream>>>(
      W1, w1t, DD, 4096, 1, 0);
  transpose_cast<<<dim3(DD / 32, 4096 / 32), tb, 0, stream>>>(
      W2, w2t, 4096, DD, 1, 0);

  // LN(x) -> hbf  and  ew = exp(pos_bias), one launch
  ln_ew_kernel<<<MM + (TT * TT / 4) / 256, 256, 0, stream>>>(
      x, g1, be1, hbf, pb, ewb);

  // q = h @ Wq + bq  -> qbf [16384,1024] bf16
  gemm_bt<EPI_Q><<<(MM / 256) * (DD / 256), 512, 0, stream>>>(
      hbf, wqt, MM, DD, DD, 0, 0, nullptr, qbf, 0, bq, nullptr, nullptr);
  // fused K+V: C[2d|2d+1, s] = [wk;wv]_interleaved @ h^T; epilogue writes
  // ekv rows 1024+d (=exp(k)) and d (=exp(k)*v) directly
  gemm_bt<EPI_KV><<<(2048 / 256) * (MM / 256), 512, 0, stream>>>(
      wkv, hbf, 2048, MM, DD, 0, 0, nullptr, nullptr, 0, bk, bv, ekv);
  // nd[b] = ew @ ekv[b]^T : [2048,2048] bf16 per batch (XCD = batch)
  gemm_bt<EPI_ND><<<BB * (TT / 256) * (TT / 256), 512, 0, stream>>>(
      ewb, ekv, TT, TT, TT, 0, (long long)TT * TT, nullptr, nd,
      (long long)TT * TT, nullptr, nullptr, nullptr);

  // fused: x2 = sigmoid(q)*num/den + x ; hbf = LN(x2)
  combine_ln_kernel<<<MM, 256, 0, stream>>>(qbf, nd, x, g2, be2, x2, hbf);

  // mid = relu(h2 @ W1 + b1) bf16 [16384,4096]
  gemm_bt<EPI_MLP1><<<(MM / 256) * (4096 / 256), 512, 0, stream>>>(
      hbf, w1t, MM, 4096, DD, 0, 0, nullptr, mid, 0, bm1, nullptr, nullptr);
  // out = mid @ W2 + b2 + x2 fp32 [16384,1024]  (add == Cf, safe)
  gemm_bt<EPI_MLP2><<<(MM / 256) * (DD / 256), 512, 0, stream>>>(
      mid, w2t, MM, DD, 4096, 0, 0, out, nullptr, 0, bm2, x2, nullptr);
}